// Round 2
// baseline (247.214 us; speedup 1.0000x reference)
//
#include <hip/hip_runtime.h>
#include <hip/hip_bf16.h>
#include <stdint.h>

typedef unsigned short u16;
typedef short bf16x8 __attribute__((ext_vector_type(8)));
typedef float f32x4 __attribute__((ext_vector_type(4)));
typedef u16 u16x4 __attribute__((ext_vector_type(4)));

#define DIMX  1024
#define NHEAD 16
#define DH    64
#define INNER 1024
#define BATCH 2
#define SEQ   2048
#define MTOT  (BATCH*SEQ)   /* 4096 */
#define EQKV  (3*INNER)     /* 3072 */

#define BM 128
#define BN 128
#define BK 64

__device__ __forceinline__ u16 f2bf(float f) {
  unsigned int x = __float_as_uint(f);
  unsigned int r = (x + 0x7FFFu + ((x >> 16) & 1u)) >> 16;
  return (u16)r;
}

__device__ __forceinline__ void async16(void* lds, const void* g) {
  __builtin_amdgcn_global_load_lds(
      (const __attribute__((address_space(1))) unsigned int*)g,
      (__attribute__((address_space(3))) unsigned int*)lds,
      16, 0, 0);
}

// ---------------- fp32 -> bf16 convert ----------------
__global__ void cvt_kernel(const float* __restrict__ in, u16* __restrict__ out, int n4) {
  int i = blockIdx.x * blockDim.x + threadIdx.x;
  if (i < n4) {
    float4 v = ((const float4*)in)[i];
    u16x4 o;
    o[0] = f2bf(v.x); o[1] = f2bf(v.y); o[2] = f2bf(v.z); o[3] = f2bf(v.w);
    ((u16x4*)out)[i] = o;
  }
}

// ---------------- QKV projection GEMM ----------------
__global__ __launch_bounds__(256) void gemm_qkv(const u16* __restrict__ X, const u16* __restrict__ W,
                                                u16* __restrict__ Qo, u16* __restrict__ Ko,
                                                u16* __restrict__ Vt) {
  __shared__ short sA[BM*BK];
  __shared__ short sB[BN*BK];
  const int tid = threadIdx.x;
  const int wv = tid >> 6, l = tid & 63;
  const int lo = l & 15, hi = l >> 4;
  const int tn = blockIdx.x * BN;
  const int tm = blockIdx.y * BM;
  const int wr = wv >> 1, wc = wv & 1;

  f32x4 acc[4][4];
#pragma unroll
  for (int i = 0; i < 4; i++)
#pragma unroll
    for (int j = 0; j < 4; j++) acc[i][j] = (f32x4){0.f, 0.f, 0.f, 0.f};

  for (int k0 = 0; k0 < DIMX; k0 += BK) {
#pragma unroll
    for (int c = 0; c < 4; c++) {
      int rbase = (c * 4 + wv) * 8;
      async16(&sA[rbase * BK], &X[(size_t)(tm + rbase + (l >> 3)) * DIMX + k0 + (l & 7) * 8]);
      async16(&sB[rbase * BK], &W[(size_t)(tn + rbase + (l >> 3)) * DIMX + k0 + (l & 7) * 8]);
    }
    __syncthreads();
#pragma unroll
    for (int ks = 0; ks < 2; ks++) {
      bf16x8 af[4], bf[4];
#pragma unroll
      for (int i = 0; i < 4; i++) af[i] = *(const bf16x8*)&sA[(wr * 64 + i * 16 + lo) * BK + ks * 32 + hi * 8];
#pragma unroll
      for (int j = 0; j < 4; j++) bf[j] = *(const bf16x8*)&sB[(wc * 64 + j * 16 + lo) * BK + ks * 32 + hi * 8];
#pragma unroll
      for (int i = 0; i < 4; i++)
#pragma unroll
        for (int j = 0; j < 4; j++)
          acc[i][j] = __builtin_amdgcn_mfma_f32_16x16x32_bf16(af[i], bf[j], acc[i][j], 0, 0, 0);
    }
    __syncthreads();
  }

  const float scale = 0.125f;  // 64^-0.5
#pragma unroll
  for (int i = 0; i < 4; i++) {
    int mbase = tm + wr * 64 + i * 16 + hi * 4;
#pragma unroll
    for (int j = 0; j < 4; j++) {
      int e = tn + wc * 64 + j * 16 + lo;
#pragma unroll
      for (int r = 0; r < 4; r++) {
        int mm = mbase + r;
        int b = mm >> 11, n = mm & 2047;
        float v = acc[i][j][r];
        if (e < INNER) {
          int h = e >> 6, d = e & 63;
          Qo[(((size_t)(b * NHEAD + h)) * SEQ + n) * DH + d] = f2bf(v * scale);
        } else if (e < 2 * INNER) {
          int e2 = e - INNER; int h = e2 >> 6, d = e2 & 63;
          Ko[(((size_t)(b * NHEAD + h)) * SEQ + n) * DH + d] = f2bf(v);
        } else {
          int e2 = e - 2 * INNER; int h = e2 >> 6, d = e2 & 63;
          Vt[(((size_t)(b * NHEAD + h)) * DH + d) * SEQ + n] = f2bf(v);
        }
      }
    }
  }
}

// ---------------- flash attention ----------------
// Q,K: [B*H][N][64] bf16 (Q pre-scaled); Vt: [B*H][64][N] bf16; O: [B*N][1024] bf16
// LDS layout: 16B unit (col16) swizzled by row&7 (T2/G4). K/V staged via
// global_load_lds with PRE-SWIZZLED global source (LDS dest linear, rule #21).
__global__ __launch_bounds__(256) void attn_kernel(const u16* __restrict__ Q, const u16* __restrict__ Kd,
                                                   const u16* __restrict__ Vt, u16* __restrict__ O) {
  __shared__ short sK[2][64 * 64];
  __shared__ short sV[2][64 * 64];
  __shared__ short sP[4][32 * 64];
  const int tid = threadIdx.x, wv = tid >> 6, l = tid & 63;
  const int lo = l & 15, hi = l >> 4;
  const int lo7 = lo & 7;

  // XCD swizzle: 512 blocks, 8 XCDs -> all 16 q-tiles of a head on one XCD
  int lin = blockIdx.y * gridDim.x + blockIdx.x;
  int wgid = (lin & 7) * 64 + (lin >> 3);
  int bx = wgid & 15;
  int bh = wgid >> 4;

  const int qw = bx * 128 + wv * 32;
  const u16* Qb = Q + (size_t)bh * SEQ * DH;
  const u16* Kb = Kd + (size_t)bh * SEQ * DH;
  const u16* Vb = Vt + (size_t)bh * DH * SEQ;

  bf16x8 qf[2][2];
#pragma unroll
  for (int mi = 0; mi < 2; mi++)
#pragma unroll
    for (int kd = 0; kd < 2; kd++)
      qf[mi][kd] = *(const bf16x8*)&Qb[(size_t)(qw + mi * 16 + lo) * DH + kd * 32 + hi * 8];

  f32x4 o[2][4];
  float mrun[2][4], lsum[2][4];
#pragma unroll
  for (int mi = 0; mi < 2; mi++) {
#pragma unroll
    for (int ni = 0; ni < 4; ni++) o[mi][ni] = (f32x4){0.f, 0.f, 0.f, 0.f};
#pragma unroll
    for (int r = 0; r < 4; r++) { mrun[mi][r] = -1e30f; lsum[mi][r] = 0.f; }
  }

  // stage tile t into buffer buf; global source pre-swizzled: col16 ^= row&7
  auto stage = [&](int buf, int t) {
    int kv0 = t * 64;
#pragma unroll
    for (int c = 0; c < 2; c++) {
      int rbase = wv * 16 + c * 8;
      int gr = rbase + (l >> 3);                 // row within 64-row tile
      int sc = ((l & 7) ^ (l >> 3)) * 8;         // swizzled 16B unit -> element offset
      async16(&sK[buf][rbase * 64], &Kb[(size_t)(kv0 + gr) * DH + sc]);
      async16(&sV[buf][rbase * 64], &Vb[(size_t)gr * SEQ + kv0 + sc]);
    }
  };

  stage(0, 0);
  __syncthreads();   // vmcnt(0) drain + barrier: tile 0 resident

  for (int t = 0; t < SEQ / 64; t++) {
    const int cur = t & 1;
    if (t + 1 < SEQ / 64) stage(cur ^ 1, t + 1);   // prefetch overlaps compute

    // ---- S = Q K^T (32 q rows x 64 kv cols per wave) ----
    f32x4 s[2][4];
#pragma unroll
    for (int kb = 0; kb < 4; kb++) {
      int row = kb * 16 + lo;
      bf16x8 kf0 = *(const bf16x8*)&sK[cur][row * 64 + ((0 + hi) ^ lo7) * 8];
      bf16x8 kf1 = *(const bf16x8*)&sK[cur][row * 64 + ((4 + hi) ^ lo7) * 8];
#pragma unroll
      for (int mi = 0; mi < 2; mi++) {
        f32x4 z = (f32x4){0.f, 0.f, 0.f, 0.f};
        z = __builtin_amdgcn_mfma_f32_16x16x32_bf16(qf[mi][0], kf0, z, 0, 0, 0);
        z = __builtin_amdgcn_mfma_f32_16x16x32_bf16(qf[mi][1], kf1, z, 0, 0, 0);
        s[mi][kb] = z;
      }
    }

    // ---- online softmax; l-sum kept lane-partial (reduced once at end) ----
#pragma unroll
    for (int mi = 0; mi < 2; mi++) {
#pragma unroll
      for (int r = 0; r < 4; r++) {
        float mx = fmaxf(fmaxf(s[mi][0][r], s[mi][1][r]), fmaxf(s[mi][2][r], s[mi][3][r]));
        mx = fmaxf(mx, __shfl_xor(mx, 1));
        mx = fmaxf(mx, __shfl_xor(mx, 2));
        mx = fmaxf(mx, __shfl_xor(mx, 4));
        mx = fmaxf(mx, __shfl_xor(mx, 8));
        float mnew = fmaxf(mrun[mi][r], mx);
        float alpha = __expf(mrun[mi][r] - mnew);
        mrun[mi][r] = mnew;
        float ps = 0.f;
#pragma unroll
        for (int kb = 0; kb < 4; kb++) {
          float p = __expf(s[mi][kb][r] - mnew);
          s[mi][kb][r] = p;
          ps += p;
        }
        lsum[mi][r] = lsum[mi][r] * alpha + ps;
#pragma unroll
        for (int ni = 0; ni < 4; ni++) o[mi][ni][r] *= alpha;
      }
    }

    // ---- P -> LDS (bf16, swizzled both sides; per-wave buffer, in-wave DS in-order) ----
    short* pw = &sP[wv][0];
#pragma unroll
    for (int mi = 0; mi < 2; mi++)
#pragma unroll
      for (int kb = 0; kb < 4; kb++) {
        int c16 = kb * 2 + (lo >> 3);
        int off = lo & 7;
#pragma unroll
        for (int r = 0; r < 4; r++) {
          int row = mi * 16 + hi * 4 + r;
          pw[row * 64 + ((c16 ^ (row & 7)) * 8) + off] = (short)f2bf(s[mi][kb][r]);
        }
      }

    // ---- O += P V ----
#pragma unroll
    for (int ks = 0; ks < 2; ks++) {
      bf16x8 pf[2];
#pragma unroll
      for (int mi = 0; mi < 2; mi++) {
        int row = mi * 16 + lo;
        pf[mi] = *(const bf16x8*)&pw[row * 64 + ((ks * 4 + hi) ^ lo7) * 8];
      }
#pragma unroll
      for (int ni = 0; ni < 4; ni++) {
        int row = ni * 16 + lo;
        bf16x8 vf = *(const bf16x8*)&sV[cur][row * 64 + ((ks * 4 + hi) ^ lo7) * 8];
#pragma unroll
        for (int mi = 0; mi < 2; mi++)
          o[mi][ni] = __builtin_amdgcn_mfma_f32_16x16x32_bf16(pf[mi], vf, o[mi][ni], 0, 0, 0);
      }
    }
    __syncthreads();   // drains prefetch (had full compute to land) + buffer handoff
  }

  int b = bh >> 4, h = bh & 15;
#pragma unroll
  for (int mi = 0; mi < 2; mi++) {
#pragma unroll
    for (int r = 0; r < 4; r++) {
      float rs = lsum[mi][r];
      rs += __shfl_xor(rs, 1);
      rs += __shfl_xor(rs, 2);
      rs += __shfl_xor(rs, 4);
      rs += __shfl_xor(rs, 8);
      float inv = 1.0f / rs;
      int n = qw + mi * 16 + hi * 4 + r;
#pragma unroll
      for (int ni = 0; ni < 4; ni++)
        O[((size_t)(b * SEQ + n)) * INNER + h * 64 + ni * 16 + lo] = f2bf(o[mi][ni][r] * inv);
    }
  }
}

// ---------------- output projection GEMM ----------------
__global__ __launch_bounds__(256) void gemm_out(const u16* __restrict__ A, const u16* __restrict__ W,
                                                const float* __restrict__ bias, float* __restrict__ out) {
  __shared__ short sA[BM*BK];
  __shared__ short sB[BN*BK];
  const int tid = threadIdx.x;
  const int wv = tid >> 6, l = tid & 63;
  const int lo = l & 15, hi = l >> 4;
  const int tn = blockIdx.x * BN;
  const int tm = blockIdx.y * BM;
  const int wr = wv >> 1, wc = wv & 1;

  f32x4 acc[4][4];
#pragma unroll
  for (int i = 0; i < 4; i++)
#pragma unroll
    for (int j = 0; j < 4; j++) acc[i][j] = (f32x4){0.f, 0.f, 0.f, 0.f};

  for (int k0 = 0; k0 < INNER; k0 += BK) {
#pragma unroll
    for (int c = 0; c < 4; c++) {
      int rbase = (c * 4 + wv) * 8;
      async16(&sA[rbase * BK], &A[(size_t)(tm + rbase + (l >> 3)) * INNER + k0 + (l & 7) * 8]);
      async16(&sB[rbase * BK], &W[(size_t)(tn + rbase + (l >> 3)) * INNER + k0 + (l & 7) * 8]);
    }
    __syncthreads();
#pragma unroll
    for (int ks = 0; ks < 2; ks++) {
      bf16x8 af[4], bf[4];
#pragma unroll
      for (int i = 0; i < 4; i++) af[i] = *(const bf16x8*)&sA[(wr * 64 + i * 16 + lo) * BK + ks * 32 + hi * 8];
#pragma unroll
      for (int j = 0; j < 4; j++) bf[j] = *(const bf16x8*)&sB[(wc * 64 + j * 16 + lo) * BK + ks * 32 + hi * 8];
#pragma unroll
      for (int i = 0; i < 4; i++)
#pragma unroll
        for (int j = 0; j < 4; j++)
          acc[i][j] = __builtin_amdgcn_mfma_f32_16x16x32_bf16(af[i], bf[j], acc[i][j], 0, 0, 0);
    }
    __syncthreads();
  }

#pragma unroll
  for (int i = 0; i < 4; i++) {
    int mbase = tm + wr * 64 + i * 16 + hi * 4;
#pragma unroll
    for (int j = 0; j < 4; j++) {
      int col = tn + wc * 64 + j * 16 + lo;
      float bv = bias[col];
#pragma unroll
      for (int r = 0; r < 4; r++)
        out[(size_t)(mbase + r) * DIMX + col] = acc[i][j][r] + bv;
    }
  }
}

extern "C" void kernel_launch(void* const* d_in, const int* in_sizes, int n_in,
                              void* d_out, int out_size, void* d_ws, size_t ws_size,
                              hipStream_t stream) {
  const float* x     = (const float*)d_in[0];
  const float* w_qkv = (const float*)d_in[1];
  const float* w_out = (const float*)d_in[2];
  const float* b_out = (const float*)d_in[3];

  char* ws = (char*)d_ws;
  u16* xb    = (u16*)(ws);                         // 8 MB
  u16* wqkvb = (u16*)(ws + (size_t)8  * (1<<20));  // 6 MB
  u16* woutb = (u16*)(ws + (size_t)14 * (1<<20));  // 2 MB
  u16* Qd    = (u16*)(ws + (size_t)16 * (1<<20));  // 8 MB
  u16* Kdd   = (u16*)(ws + (size_t)24 * (1<<20));  // 8 MB
  u16* Vtd   = (u16*)(ws + (size_t)32 * (1<<20));  // 8 MB
  u16* Od    = (u16*)(ws + (size_t)40 * (1<<20));  // 8 MB

  cvt_kernel<<<(MTOT * DIMX / 4 + 255) / 256, 256, 0, stream>>>(x, xb, MTOT * DIMX / 4);
  cvt_kernel<<<(EQKV * DIMX / 4 + 255) / 256, 256, 0, stream>>>(w_qkv, wqkvb, EQKV * DIMX / 4);
  cvt_kernel<<<(DIMX * INNER / 4 + 255) / 256, 256, 0, stream>>>(w_out, woutb, DIMX * INNER / 4);

  gemm_qkv<<<dim3(EQKV / BN, MTOT / BM), 256, 0, stream>>>(xb, wqkvb, Qd, Kdd, Vtd);
  attn_kernel<<<dim3(SEQ / 128, BATCH * NHEAD), 256, 0, stream>>>(Qd, Kdd, Vtd, Od);
  gemm_out<<<dim3(DIMX / BN, MTOT / BM), 256, 0, stream>>>(Od, woutb, b_out, (float*)d_out);
}

// Round 4
// 177.174 us; speedup vs baseline: 1.3953x; 1.3953x over previous
//
#include <hip/hip_runtime.h>
#include <hip/hip_bf16.h>
#include <stdint.h>

typedef unsigned short u16;
typedef short bf16x8 __attribute__((ext_vector_type(8)));
typedef float f32x4 __attribute__((ext_vector_type(4)));
typedef float f32x16 __attribute__((ext_vector_type(16)));
typedef u16 u16x4 __attribute__((ext_vector_type(4)));

#define DIMX  1024
#define NHEAD 16
#define DH    64
#define INNER 1024
#define BATCH 2
#define SEQ   2048
#define MTOT  (BATCH*SEQ)   /* 4096 */
#define EQKV  (3*INNER)     /* 3072 */

#define BM 128
#define BN 128
#define BK 64

__device__ __forceinline__ u16 f2bf(float f) {
  unsigned int x = __float_as_uint(f);
  unsigned int r = (x + 0x7FFFu + ((x >> 16) & 1u)) >> 16;
  return (u16)r;
}

// pack two f32 -> u32 of two bf16 (lo -> [15:0], hi -> [31:16]), RNE
__device__ __forceinline__ unsigned int pkbf(float lo, float hi) {
  return ((unsigned int)f2bf(hi) << 16) | (unsigned int)f2bf(lo);
}

// permlane32_swap via builtin (hazard-safe): returns {[x.lo|y.lo], [x.hi|y.hi]}
__device__ __forceinline__ void plswap_u(unsigned int& x, unsigned int& y) {
  auto r = __builtin_amdgcn_permlane32_swap(x, y, false, false);
  x = r[0]; y = r[1];
}
// combine a per-lane value with its partner lane (l ^ 32): returns {own_or_partner pair}
__device__ __forceinline__ void plswap_f2(float v, float& a, float& b) {
  unsigned int x = __float_as_uint(v), y = __float_as_uint(v);
  auto r = __builtin_amdgcn_permlane32_swap(x, y, false, false);
  a = __uint_as_float(r[0]); b = __uint_as_float(r[1]);
}

__device__ __forceinline__ void async16(void* lds, const void* g) {
  __builtin_amdgcn_global_load_lds(
      (const __attribute__((address_space(1))) unsigned int*)g,
      (__attribute__((address_space(3))) unsigned int*)lds,
      16, 0, 0);
}

// ---------------- fp32 -> bf16 convert ----------------
__global__ void cvt_kernel(const float* __restrict__ in, u16* __restrict__ out, int n4) {
  int i = blockIdx.x * blockDim.x + threadIdx.x;
  if (i < n4) {
    float4 v = ((const float4*)in)[i];
    u16x4 o;
    o[0] = f2bf(v.x); o[1] = f2bf(v.y); o[2] = f2bf(v.z); o[3] = f2bf(v.w);
    ((u16x4*)out)[i] = o;
  }
}

// ---------------- QKV projection GEMM ----------------
__global__ __launch_bounds__(256) void gemm_qkv(const u16* __restrict__ X, const u16* __restrict__ W,
                                                u16* __restrict__ Qo, u16* __restrict__ Ko,
                                                u16* __restrict__ Vt) {
  __shared__ short sA[BM*BK];
  __shared__ short sB[BN*BK];
  const int tid = threadIdx.x;
  const int wv = tid >> 6, l = tid & 63;
  const int lo = l & 15, hi = l >> 4;
  const int tn = blockIdx.x * BN;
  const int tm = blockIdx.y * BM;
  const int wr = wv >> 1, wc = wv & 1;

  f32x4 acc[4][4];
#pragma unroll
  for (int i = 0; i < 4; i++)
#pragma unroll
    for (int j = 0; j < 4; j++) acc[i][j] = (f32x4){0.f, 0.f, 0.f, 0.f};

  for (int k0 = 0; k0 < DIMX; k0 += BK) {
#pragma unroll
    for (int c = 0; c < 4; c++) {
      int rbase = (c * 4 + wv) * 8;
      async16(&sA[rbase * BK], &X[(size_t)(tm + rbase + (l >> 3)) * DIMX + k0 + (l & 7) * 8]);
      async16(&sB[rbase * BK], &W[(size_t)(tn + rbase + (l >> 3)) * DIMX + k0 + (l & 7) * 8]);
    }
    __syncthreads();
#pragma unroll
    for (int ks = 0; ks < 2; ks++) {
      bf16x8 af[4], bf[4];
#pragma unroll
      for (int i = 0; i < 4; i++) af[i] = *(const bf16x8*)&sA[(wr * 64 + i * 16 + lo) * BK + ks * 32 + hi * 8];
#pragma unroll
      for (int j = 0; j < 4; j++) bf[j] = *(const bf16x8*)&sB[(wc * 64 + j * 16 + lo) * BK + ks * 32 + hi * 8];
#pragma unroll
      for (int i = 0; i < 4; i++)
#pragma unroll
        for (int j = 0; j < 4; j++)
          acc[i][j] = __builtin_amdgcn_mfma_f32_16x16x32_bf16(af[i], bf[j], acc[i][j], 0, 0, 0);
    }
    __syncthreads();
  }

  const float scale = 0.125f;  // 64^-0.5
#pragma unroll
  for (int i = 0; i < 4; i++) {
    int mbase = tm + wr * 64 + i * 16 + hi * 4;
#pragma unroll
    for (int j = 0; j < 4; j++) {
      int e = tn + wc * 64 + j * 16 + lo;
#pragma unroll
      for (int r = 0; r < 4; r++) {
        int mm = mbase + r;
        int b = mm >> 11, n = mm & 2047;
        float v = acc[i][j][r];
        if (e < INNER) {
          int h = e >> 6, d = e & 63;
          Qo[(((size_t)(b * NHEAD + h)) * SEQ + n) * DH + d] = f2bf(v * scale);
        } else if (e < 2 * INNER) {
          int e2 = e - INNER; int h = e2 >> 6, d = e2 & 63;
          Ko[(((size_t)(b * NHEAD + h)) * SEQ + n) * DH + d] = f2bf(v);
        } else {
          int e2 = e - 2 * INNER; int h = e2 >> 6, d = e2 & 63;
          Vt[(((size_t)(b * NHEAD + h)) * DH + d) * SEQ + n] = f2bf(v);
        }
      }
    }
  }
}

// ---------------- flash attention (32x32 swapped QK^T, in-register softmax) ----------------
// Q,K: [B*H][N][64] bf16 (Q pre-scaled); Vt: [B*H][64][N] bf16; O: [B*N][1024] bf16
// Per wave: 32 q's (q = qw + lane&31; lanes l and l^32 are partners on the same q).
// S^T = mfma(A=K, B=Q): C col=lane&31=q, row kv=(reg&3)+8*(reg>>2)+4*(lane>>5).
// Softmax in-register: 16-reg tree + 1 permlane32_swap (builtin). P repacked to
// the PV B-frag via bf16 pack + permlane32_swap. PV: O^T = mfma(A=V^T, B=P^T),
// accumulator col = q -> alpha/lsum are per-lane scalars.
__global__ __launch_bounds__(256) void attn_kernel(const u16* __restrict__ Q, const u16* __restrict__ Kd,
                                                   const u16* __restrict__ Vt, u16* __restrict__ O) {
  __shared__ short sK[2][64 * 64];
  __shared__ short sV[2][64 * 64];
  const int tid = threadIdx.x, wv = tid >> 6, l = tid & 63;
  const int l31 = l & 31, hi5 = l >> 5, l7 = l & 7;

  // XCD swizzle: 512 blocks -> all 16 q-blocks of a head per XCD
  int lin = blockIdx.y * gridDim.x + blockIdx.x;
  int wgid = (lin & 7) * 64 + (lin >> 3);
  int bx = wgid & 15;
  int bh = wgid >> 4;

  const int qw = bx * 128 + wv * 32;
  const u16* Qb = Q + (size_t)bh * SEQ * DH;
  const u16* Kb = Kd + (size_t)bh * SEQ * DH;
  const u16* Vb = Vt + (size_t)bh * DH * SEQ;

  // Q as MFMA B-frag: n=q=lane&31, k=d = kd*16 + hi5*8 + j
  bf16x8 qf[4];
#pragma unroll
  for (int kd = 0; kd < 4; kd++)
    qf[kd] = *(const bf16x8*)&Qb[(size_t)(qw + l31) * DH + kd * 16 + hi5 * 8];

  f32x16 o0, o1;
#pragma unroll
  for (int r = 0; r < 16; r++) { o0[r] = 0.f; o1[r] = 0.f; }
  float mrun = -1e30f, lsum = 0.f;

  auto stage = [&](int buf, int t) {
    int kv0 = t * 64;
#pragma unroll
    for (int c = 0; c < 2; c++) {
      int rbase = wv * 16 + c * 8;
      int gr = rbase + (l >> 3);
      int sc = ((l & 7) ^ (l >> 3)) * 8;
      async16(&sK[buf][rbase * 64], &Kb[(size_t)(kv0 + gr) * DH + sc]);
      async16(&sV[buf][rbase * 64], &Vb[(size_t)gr * SEQ + kv0 + sc]);
    }
  };

  stage(0, 0);
  __syncthreads();

  for (int t = 0; t < SEQ / 64; t++) {
    const int cur = t & 1;
    if (t + 1 < SEQ / 64) stage(cur ^ 1, t + 1);

    // ---- S^T = K Q^T : two 32-kv chunks, accumulate over d ----
    f32x16 s0, s1;
#pragma unroll
    for (int r = 0; r < 16; r++) { s0[r] = 0.f; s1[r] = 0.f; }
#pragma unroll
    for (int kd = 0; kd < 4; kd++) {
      int c16 = ((kd * 2 + hi5) ^ l7) * 8;
      bf16x8 k0 = *(const bf16x8*)&sK[cur][l31 * 64 + c16];
      bf16x8 k1 = *(const bf16x8*)&sK[cur][(32 + l31) * 64 + c16];
      s0 = __builtin_amdgcn_mfma_f32_32x32x16_bf16(k0, qf[kd], s0, 0, 0, 0);
      s1 = __builtin_amdgcn_mfma_f32_32x32x16_bf16(k1, qf[kd], s1, 0, 0, 0);
    }

    // ---- in-register online softmax (per-lane q) ----
    float tr[16];
#pragma unroll
    for (int r = 0; r < 16; r++) tr[r] = fmaxf(s0[r], s1[r]);
#pragma unroll
    for (int st = 8; st > 0; st >>= 1)
#pragma unroll
      for (int r = 0; r < st; r++) tr[r] = fmaxf(tr[r], tr[r + st]);
    float mxa, mxb;
    plswap_f2(tr[0], mxa, mxb);          // own/partner pair
    float mx = fmaxf(mxa, mxb);
    float mnew = fmaxf(mrun, mx);
    float alpha = __expf(mrun - mnew);
    mrun = mnew;

    float sm[16];
#pragma unroll
    for (int r = 0; r < 16; r++) {
      s0[r] = __expf(s0[r] - mnew);
      s1[r] = __expf(s1[r] - mnew);
      sm[r] = s0[r] + s1[r];
    }
#pragma unroll
    for (int st = 8; st > 0; st >>= 1)
#pragma unroll
      for (int r = 0; r < st; r++) sm[r] += sm[r + st];
    lsum = lsum * alpha + sm[0];
    o0 *= alpha;
    o1 *= alpha;

    // ---- P (f32 C-layout) -> PV B-frags via pack + permlane32_swap ----
    // B-frag slice ks: lane needs P^T[kv = ks*16 + hi5*8 + j][q], words (j>>1)
    bf16x8 pa[4];
#pragma unroll
    for (int ks = 0; ks < 4; ks++) {
      const int sft = (ks & 1) * 8;
      float e0 = (ks < 2) ? s0[sft + 0] : s1[sft + 0];
      float e1 = (ks < 2) ? s0[sft + 1] : s1[sft + 1];
      float e2 = (ks < 2) ? s0[sft + 2] : s1[sft + 2];
      float e3 = (ks < 2) ? s0[sft + 3] : s1[sft + 3];
      float e4 = (ks < 2) ? s0[sft + 4] : s1[sft + 4];
      float e5 = (ks < 2) ? s0[sft + 5] : s1[sft + 5];
      float e6 = (ks < 2) ? s0[sft + 6] : s1[sft + 6];
      float e7 = (ks < 2) ? s0[sft + 7] : s1[sft + 7];
      unsigned int w0 = pkbf(e0, e1);   // rows (0,1)+base   | partner rows (4,5)+base
      unsigned int w1 = pkbf(e2, e3);
      unsigned int w2 = pkbf(e4, e5);   // rows (8,9)+base   | partner rows (12,13)+base
      unsigned int w3 = pkbf(e6, e7);
      plswap_u(w0, w2);                 // w0 -> frag word0, w2 -> frag word2
      plswap_u(w1, w3);                 // w1 -> frag word1, w3 -> frag word3
      union { unsigned int w[4]; bf16x8 v; } u;
      u.w[0] = w0; u.w[1] = w1; u.w[2] = w2; u.w[3] = w3;
      pa[ks] = u.v;
    }

    // ---- O^T += V^T P^T : A = V^T (m=dv), B = P^T (n=q) ----
#pragma unroll
    for (int ks = 0; ks < 4; ks++) {
      int c16 = ((ks * 2 + hi5) ^ l7) * 8;
      bf16x8 v0 = *(const bf16x8*)&sV[cur][l31 * 64 + c16];
      bf16x8 v1 = *(const bf16x8*)&sV[cur][(32 + l31) * 64 + c16];
      o0 = __builtin_amdgcn_mfma_f32_32x32x16_bf16(v0, pa[ks], o0, 0, 0, 0);
      o1 = __builtin_amdgcn_mfma_f32_32x32x16_bf16(v1, pa[ks], o1, 0, 0, 0);
    }
    __syncthreads();
  }

  // ---- finalize: combine partner lsum, normalize, store ----
  float la, lb;
  plswap_f2(lsum, la, lb);
  float inv = 1.0f / (la + lb);

  int b = bh >> 4, h = bh & 15;
  int q = qw + l31;
  size_t orow = ((size_t)(b * SEQ + q)) * INNER + h * 64;
#pragma unroll
  for (int half = 0; half < 2; half++) {
    const f32x16& oo = half ? o1 : o0;
#pragma unroll
    for (int g = 0; g < 4; g++) {
      u16x4 pk4;
#pragma unroll
      for (int e = 0; e < 4; e++) pk4[e] = f2bf(oo[g * 4 + e] * inv);
      int dv = half * 32 + g * 8 + 4 * hi5;
      *(u16x4*)&O[orow + dv] = pk4;
    }
  }
}

// ---------------- output projection GEMM ----------------
__global__ __launch_bounds__(256) void gemm_out(const u16* __restrict__ A, const u16* __restrict__ W,
                                                const float* __restrict__ bias, float* __restrict__ out) {
  __shared__ short sA[BM*BK];
  __shared__ short sB[BN*BK];
  const int tid = threadIdx.x;
  const int wv = tid >> 6, l = tid & 63;
  const int lo = l & 15, hi = l >> 4;
  const int tn = blockIdx.x * BN;
  const int tm = blockIdx.y * BM;
  const int wr = wv >> 1, wc = wv & 1;

  f32x4 acc[4][4];
#pragma unroll
  for (int i = 0; i < 4; i++)
#pragma unroll
    for (int j = 0; j < 4; j++) acc[i][j] = (f32x4){0.f, 0.f, 0.f, 0.f};

  for (int k0 = 0; k0 < INNER; k0 += BK) {
#pragma unroll
    for (int c = 0; c < 4; c++) {
      int rbase = (c * 4 + wv) * 8;
      async16(&sA[rbase * BK], &A[(size_t)(tm + rbase + (l >> 3)) * INNER + k0 + (l & 7) * 8]);
      async16(&sB[rbase * BK], &W[(size_t)(tn + rbase + (l >> 3)) * INNER + k0 + (l & 7) * 8]);
    }
    __syncthreads();
#pragma unroll
    for (int ks = 0; ks < 2; ks++) {
      bf16x8 af[4], bf[4];
#pragma unroll
      for (int i = 0; i < 4; i++) af[i] = *(const bf16x8*)&sA[(wr * 64 + i * 16 + lo) * BK + ks * 32 + hi * 8];
#pragma unroll
      for (int j = 0; j < 4; j++) bf[j] = *(const bf16x8*)&sB[(wc * 64 + j * 16 + lo) * BK + ks * 32 + hi * 8];
#pragma unroll
      for (int i = 0; i < 4; i++)
#pragma unroll
        for (int j = 0; j < 4; j++)
          acc[i][j] = __builtin_amdgcn_mfma_f32_16x16x32_bf16(af[i], bf[j], acc[i][j], 0, 0, 0);
    }
    __syncthreads();
  }

#pragma unroll
  for (int i = 0; i < 4; i++) {
    int mbase = tm + wr * 64 + i * 16 + hi * 4;
#pragma unroll
    for (int j = 0; j < 4; j++) {
      int col = tn + wc * 64 + j * 16 + lo;
      float bv = bias[col];
#pragma unroll
      for (int r = 0; r < 4; r++)
        out[(size_t)(mbase + r) * DIMX + col] = acc[i][j][r] + bv;
    }
  }
}

extern "C" void kernel_launch(void* const* d_in, const int* in_sizes, int n_in,
                              void* d_out, int out_size, void* d_ws, size_t ws_size,
                              hipStream_t stream) {
  const float* x     = (const float*)d_in[0];
  const float* w_qkv = (const float*)d_in[1];
  const float* w_out = (const float*)d_in[2];
  const float* b_out = (const float*)d_in[3];

  char* ws = (char*)d_ws;
  u16* xb    = (u16*)(ws);                         // 8 MB
  u16* wqkvb = (u16*)(ws + (size_t)8  * (1<<20));  // 6 MB
  u16* woutb = (u16*)(ws + (size_t)14 * (1<<20));  // 2 MB
  u16* Qd    = (u16*)(ws + (size_t)16 * (1<<20));  // 8 MB
  u16* Kdd   = (u16*)(ws + (size_t)24 * (1<<20));  // 8 MB
  u16* Vtd   = (u16*)(ws + (size_t)32 * (1<<20));  // 8 MB
  u16* Od    = (u16*)(ws + (size_t)40 * (1<<20));  // 8 MB

  cvt_kernel<<<(MTOT * DIMX / 4 + 255) / 256, 256, 0, stream>>>(x, xb, MTOT * DIMX / 4);
  cvt_kernel<<<(EQKV * DIMX / 4 + 255) / 256, 256, 0, stream>>>(w_qkv, wqkvb, EQKV * DIMX / 4);
  cvt_kernel<<<(DIMX * INNER / 4 + 255) / 256, 256, 0, stream>>>(w_out, woutb, DIMX * INNER / 4);

  gemm_qkv<<<dim3(EQKV / BN, MTOT / BM), 256, 0, stream>>>(xb, wqkvb, Qd, Kdd, Vtd);
  attn_kernel<<<dim3(SEQ / 128, BATCH * NHEAD), 256, 0, stream>>>(Qd, Kdd, Vtd, Od);
  gemm_out<<<dim3(DIMX / BN, MTOT / BM), 256, 0, stream>>>(Od, woutb, b_out, (float*)d_out);
}

// Round 5
// 155.318 us; speedup vs baseline: 1.5917x; 1.1407x over previous
//
#include <hip/hip_runtime.h>
#include <hip/hip_bf16.h>
#include <stdint.h>

typedef unsigned short u16;
typedef short bf16x8 __attribute__((ext_vector_type(8)));
typedef float f32x4 __attribute__((ext_vector_type(4)));
typedef float f32x16 __attribute__((ext_vector_type(16)));
typedef u16 u16x4 __attribute__((ext_vector_type(4)));
typedef unsigned int uint2v __attribute__((ext_vector_type(2)));

#define DIMX  1024
#define NHEAD 16
#define DH    64
#define INNER 1024
#define BATCH 2
#define SEQ   2048
#define MTOT  (BATCH*SEQ)   /* 4096 */
#define EQKV  (3*INNER)     /* 3072 */

#define BM 128
#define BN 128
#define BK 64

__device__ __forceinline__ u16 f2bf(float f) {
  unsigned int x = __float_as_uint(f);
  unsigned int r = (x + 0x7FFFu + ((x >> 16) & 1u)) >> 16;
  return (u16)r;
}

// v_cvt_pk_bf16_f32: two f32 -> one u32 of 2 bf16 (lo->[15:0], hi->[31:16]), RNE.
// Plain VOP3 VALU op — no permlane-class hazard (round-3 failure isolated to asm permlane).
__device__ __forceinline__ unsigned int cvtpk(float lo, float hi) {
  unsigned int r;
  asm("v_cvt_pk_bf16_f32 %0, %1, %2" : "=v"(r) : "v"(lo), "v"(hi));
  return r;
}

// permlane32_swap via builtin (hazard-safe): returns {[x.lo|y.lo], [x.hi|y.hi]}
__device__ __forceinline__ void plswap_u(unsigned int& x, unsigned int& y) {
  auto r = __builtin_amdgcn_permlane32_swap(x, y, false, false);
  x = r[0]; y = r[1];
}
__device__ __forceinline__ void plswap_f2(float v, float& a, float& b) {
  unsigned int x = __float_as_uint(v), y = __float_as_uint(v);
  auto r = __builtin_amdgcn_permlane32_swap(x, y, false, false);
  a = __uint_as_float(r[0]); b = __uint_as_float(r[1]);
}

__device__ __forceinline__ void async16(void* lds, const void* g) {
  __builtin_amdgcn_global_load_lds(
      (const __attribute__((address_space(1))) unsigned int*)g,
      (__attribute__((address_space(3))) unsigned int*)lds,
      16, 0, 0);
}

// ---------------- fp32 -> bf16 convert ----------------
__global__ void cvt_kernel(const float* __restrict__ in, u16* __restrict__ out, int n4) {
  int i = blockIdx.x * blockDim.x + threadIdx.x;
  if (i < n4) {
    float4 v = ((const float4*)in)[i];
    u16x4 o;
    o[0] = f2bf(v.x); o[1] = f2bf(v.y); o[2] = f2bf(v.z); o[3] = f2bf(v.w);
    ((u16x4*)out)[i] = o;
  }
}

// ---------------- QKV projection GEMM ----------------
__global__ __launch_bounds__(256) void gemm_qkv(const u16* __restrict__ X, const u16* __restrict__ W,
                                                u16* __restrict__ Qo, u16* __restrict__ Ko,
                                                u16* __restrict__ Vt) {
  __shared__ short sA[BM*BK];
  __shared__ short sB[BN*BK];
  const int tid = threadIdx.x;
  const int wv = tid >> 6, l = tid & 63;
  const int lo = l & 15, hi = l >> 4;
  const int tn = blockIdx.x * BN;
  const int tm = blockIdx.y * BM;
  const int wr = wv >> 1, wc = wv & 1;

  f32x4 acc[4][4];
#pragma unroll
  for (int i = 0; i < 4; i++)
#pragma unroll
    for (int j = 0; j < 4; j++) acc[i][j] = (f32x4){0.f, 0.f, 0.f, 0.f};

  for (int k0 = 0; k0 < DIMX; k0 += BK) {
#pragma unroll
    for (int c = 0; c < 4; c++) {
      int rbase = (c * 4 + wv) * 8;
      async16(&sA[rbase * BK], &X[(size_t)(tm + rbase + (l >> 3)) * DIMX + k0 + (l & 7) * 8]);
      async16(&sB[rbase * BK], &W[(size_t)(tn + rbase + (l >> 3)) * DIMX + k0 + (l & 7) * 8]);
    }
    __syncthreads();
#pragma unroll
    for (int ks = 0; ks < 2; ks++) {
      bf16x8 af[4], bf[4];
#pragma unroll
      for (int i = 0; i < 4; i++) af[i] = *(const bf16x8*)&sA[(wr * 64 + i * 16 + lo) * BK + ks * 32 + hi * 8];
#pragma unroll
      for (int j = 0; j < 4; j++) bf[j] = *(const bf16x8*)&sB[(wc * 64 + j * 16 + lo) * BK + ks * 32 + hi * 8];
#pragma unroll
      for (int i = 0; i < 4; i++)
#pragma unroll
        for (int j = 0; j < 4; j++)
          acc[i][j] = __builtin_amdgcn_mfma_f32_16x16x32_bf16(af[i], bf[j], acc[i][j], 0, 0, 0);
    }
    __syncthreads();
  }

  // Q pre-scale folded with log2(e): softmax runs in exp2 domain downstream
  const float scale = 0.125f * 1.44269504088896f;
#pragma unroll
  for (int i = 0; i < 4; i++) {
    int mbase = tm + wr * 64 + i * 16 + hi * 4;
#pragma unroll
    for (int j = 0; j < 4; j++) {
      int e = tn + wc * 64 + j * 16 + lo;
#pragma unroll
      for (int r = 0; r < 4; r++) {
        int mm = mbase + r;
        int b = mm >> 11, n = mm & 2047;
        float v = acc[i][j][r];
        if (e < INNER) {
          int h = e >> 6, d = e & 63;
          Qo[(((size_t)(b * NHEAD + h)) * SEQ + n) * DH + d] = f2bf(v * scale);
        } else if (e < 2 * INNER) {
          int e2 = e - INNER; int h = e2 >> 6, d = e2 & 63;
          Ko[(((size_t)(b * NHEAD + h)) * SEQ + n) * DH + d] = f2bf(v);
        } else {
          int e2 = e - 2 * INNER; int h = e2 >> 6, d = e2 & 63;
          Vt[(((size_t)(b * NHEAD + h)) * DH + d) * SEQ + n] = f2bf(v);
        }
      }
    }
  }
}

// ---------------- flash attention (32x32 swapped QK^T, in-register log2-softmax) ----------------
// Q,K: [B*H][N][64] bf16 (Q pre-scaled by dh^-0.5 * log2e); Vt: [B*H][64][N]; O: [B*N][1024]
// Per wave: 32 q's (q = qw + lane&31; lanes l and l^32 are partners on the same q).
// S^T = mfma(A=K, B=Q) in log2 units. Softmax in-register: tree + 1 permlane32_swap.
// T13 defer-max: skip mrun-update/rescale while tile max stays within THR of mrun.
// P repacked to PV B-frag via v_cvt_pk_bf16_f32 (asm) + permlane32_swap (builtin).
// PV: O^T = mfma(A=V^T, B=P^T): accumulator col = q -> per-lane scalar rescale/lsum.
__global__ __launch_bounds__(256) void attn_kernel(const u16* __restrict__ Q, const u16* __restrict__ Kd,
                                                   const u16* __restrict__ Vt, u16* __restrict__ O) {
  __shared__ short sK[2][64 * 64];
  __shared__ short sV[2][64 * 64];
  const int tid = threadIdx.x, wv = tid >> 6, l = tid & 63;
  const int l31 = l & 31, hi5 = l >> 5, l7 = l & 7;

  // XCD swizzle: 512 blocks -> all 16 q-blocks of a head per XCD
  int lin = blockIdx.y * gridDim.x + blockIdx.x;
  int wgid = (lin & 7) * 64 + (lin >> 3);
  int bx = wgid & 15;
  int bh = wgid >> 4;

  const int qw = bx * 128 + wv * 32;
  const u16* Qb = Q + (size_t)bh * SEQ * DH;
  const u16* Kb = Kd + (size_t)bh * SEQ * DH;
  const u16* Vb = Vt + (size_t)bh * DH * SEQ;

  bf16x8 qf[4];
#pragma unroll
  for (int kd = 0; kd < 4; kd++)
    qf[kd] = *(const bf16x8*)&Qb[(size_t)(qw + l31) * DH + kd * 16 + hi5 * 8];

  f32x16 o0, o1;
#pragma unroll
  for (int r = 0; r < 16; r++) { o0[r] = 0.f; o1[r] = 0.f; }
  float mrun = -1e30f, lsum = 0.f;
  const float THR = 11.0f;   // log2 units (~e^7.6); P bounded by 2^11 -> safe in bf16

  auto stage = [&](int buf, int t) {
    int kv0 = t * 64;
#pragma unroll
    for (int c = 0; c < 2; c++) {
      int rbase = wv * 16 + c * 8;
      int gr = rbase + (l >> 3);
      int sc = ((l & 7) ^ (l >> 3)) * 8;
      async16(&sK[buf][rbase * 64], &Kb[(size_t)(kv0 + gr) * DH + sc]);
      async16(&sV[buf][rbase * 64], &Vb[(size_t)gr * SEQ + kv0 + sc]);
    }
  };

  stage(0, 0);
  __syncthreads();

  for (int t = 0; t < SEQ / 64; t++) {
    const int cur = t & 1;
    if (t + 1 < SEQ / 64) stage(cur ^ 1, t + 1);

    // ---- S^T = K Q^T : two 32-kv chunks, accumulate over d ----
    f32x16 s0, s1;
#pragma unroll
    for (int r = 0; r < 16; r++) { s0[r] = 0.f; s1[r] = 0.f; }
#pragma unroll
    for (int kd = 0; kd < 4; kd++) {
      int c16 = ((kd * 2 + hi5) ^ l7) * 8;
      bf16x8 k0 = *(const bf16x8*)&sK[cur][l31 * 64 + c16];
      bf16x8 k1 = *(const bf16x8*)&sK[cur][(32 + l31) * 64 + c16];
      s0 = __builtin_amdgcn_mfma_f32_32x32x16_bf16(k0, qf[kd], s0, 0, 0, 0);
      s1 = __builtin_amdgcn_mfma_f32_32x32x16_bf16(k1, qf[kd], s1, 0, 0, 0);
    }

    // ---- in-register online softmax (log2 domain, per-lane q) ----
    float tr[16];
#pragma unroll
    for (int r = 0; r < 16; r++) tr[r] = fmaxf(s0[r], s1[r]);
#pragma unroll
    for (int st = 8; st > 0; st >>= 1)
#pragma unroll
      for (int r = 0; r < st; r++) tr[r] = fmaxf(tr[r], tr[r + st]);
    float mxa, mxb;
    plswap_f2(tr[0], mxa, mxb);
    float mx = fmaxf(mxa, mxb);

    // T13 defer-max: only rescale when some lane's tile-max exceeds mrun+THR
    if (!__all(mx <= mrun + THR)) {
      float mnew = fmaxf(mrun, mx);
      float alpha = __builtin_amdgcn_exp2f(mrun - mnew);
      mrun = mnew;
      lsum *= alpha;
      o0 *= alpha;
      o1 *= alpha;
    }

    float sm[16];
#pragma unroll
    for (int r = 0; r < 16; r++) {
      s0[r] = __builtin_amdgcn_exp2f(s0[r] - mrun);
      s1[r] = __builtin_amdgcn_exp2f(s1[r] - mrun);
      sm[r] = s0[r] + s1[r];
    }
#pragma unroll
    for (int st = 8; st > 0; st >>= 1)
#pragma unroll
      for (int r = 0; r < st; r++) sm[r] += sm[r + st];
    lsum += sm[0];

    // ---- P (f32 C-layout) -> PV B-frags via cvt_pk + permlane32_swap ----
    bf16x8 pa[4];
#pragma unroll
    for (int ks = 0; ks < 4; ks++) {
      const int sft = (ks & 1) * 8;
      float e0 = (ks < 2) ? s0[sft + 0] : s1[sft + 0];
      float e1 = (ks < 2) ? s0[sft + 1] : s1[sft + 1];
      float e2 = (ks < 2) ? s0[sft + 2] : s1[sft + 2];
      float e3 = (ks < 2) ? s0[sft + 3] : s1[sft + 3];
      float e4 = (ks < 2) ? s0[sft + 4] : s1[sft + 4];
      float e5 = (ks < 2) ? s0[sft + 5] : s1[sft + 5];
      float e6 = (ks < 2) ? s0[sft + 6] : s1[sft + 6];
      float e7 = (ks < 2) ? s0[sft + 7] : s1[sft + 7];
      unsigned int w0 = cvtpk(e0, e1);
      unsigned int w1 = cvtpk(e2, e3);
      unsigned int w2 = cvtpk(e4, e5);
      unsigned int w3 = cvtpk(e6, e7);
      plswap_u(w0, w2);
      plswap_u(w1, w3);
      union { unsigned int w[4]; bf16x8 v; } u;
      u.w[0] = w0; u.w[1] = w1; u.w[2] = w2; u.w[3] = w3;
      pa[ks] = u.v;
    }

    // ---- O^T += V^T P^T ----
#pragma unroll
    for (int ks = 0; ks < 4; ks++) {
      int c16 = ((ks * 2 + hi5) ^ l7) * 8;
      bf16x8 v0 = *(const bf16x8*)&sV[cur][l31 * 64 + c16];
      bf16x8 v1 = *(const bf16x8*)&sV[cur][(32 + l31) * 64 + c16];
      o0 = __builtin_amdgcn_mfma_f32_32x32x16_bf16(v0, pa[ks], o0, 0, 0, 0);
      o1 = __builtin_amdgcn_mfma_f32_32x32x16_bf16(v1, pa[ks], o1, 0, 0, 0);
    }
    __syncthreads();
  }

  // ---- finalize: combine partner lsum, normalize, store (cvt_pk epilogue) ----
  float la, lb;
  plswap_f2(lsum, la, lb);
  float inv = 1.0f / (la + lb);

  int b = bh >> 4, h = bh & 15;
  int q = qw + l31;
  size_t orow = ((size_t)(b * SEQ + q)) * INNER + h * 64;
#pragma unroll
  for (int half = 0; half < 2; half++) {
    const f32x16& oo = half ? o1 : o0;
#pragma unroll
    for (int g = 0; g < 4; g++) {
      uint2v pk2;
      pk2[0] = cvtpk(oo[g * 4 + 0] * inv, oo[g * 4 + 1] * inv);
      pk2[1] = cvtpk(oo[g * 4 + 2] * inv, oo[g * 4 + 3] * inv);
      int dv = half * 32 + g * 8 + 4 * hi5;
      *(uint2v*)&O[orow + dv] = pk2;
    }
  }
}

// ---------------- output projection GEMM ----------------
__global__ __launch_bounds__(256) void gemm_out(const u16* __restrict__ A, const u16* __restrict__ W,
                                                const float* __restrict__ bias, float* __restrict__ out) {
  __shared__ short sA[BM*BK];
  __shared__ short sB[BN*BK];
  const int tid = threadIdx.x;
  const int wv = tid >> 6, l = tid & 63;
  const int lo = l & 15, hi = l >> 4;
  const int tn = blockIdx.x * BN;
  const int tm = blockIdx.y * BM;
  const int wr = wv >> 1, wc = wv & 1;

  f32x4 acc[4][4];
#pragma unroll
  for (int i = 0; i < 4; i++)
#pragma unroll
    for (int j = 0; j < 4; j++) acc[i][j] = (f32x4){0.f, 0.f, 0.f, 0.f};

  for (int k0 = 0; k0 < INNER; k0 += BK) {
#pragma unroll
    for (int c = 0; c < 4; c++) {
      int rbase = (c * 4 + wv) * 8;
      async16(&sA[rbase * BK], &A[(size_t)(tm + rbase + (l >> 3)) * INNER + k0 + (l & 7) * 8]);
      async16(&sB[rbase * BK], &W[(size_t)(tn + rbase + (l >> 3)) * INNER + k0 + (l & 7) * 8]);
    }
    __syncthreads();
#pragma unroll
    for (int ks = 0; ks < 2; ks++) {
      bf16x8 af[4], bf[4];
#pragma unroll
      for (int i = 0; i < 4; i++) af[i] = *(const bf16x8*)&sA[(wr * 64 + i * 16 + lo) * BK + ks * 32 + hi * 8];
#pragma unroll
      for (int j = 0; j < 4; j++) bf[j] = *(const bf16x8*)&sB[(wc * 64 + j * 16 + lo) * BK + ks * 32 + hi * 8];
#pragma unroll
      for (int i = 0; i < 4; i++)
#pragma unroll
        for (int j = 0; j < 4; j++)
          acc[i][j] = __builtin_amdgcn_mfma_f32_16x16x32_bf16(af[i], bf[j], acc[i][j], 0, 0, 0);
    }
    __syncthreads();
  }

#pragma unroll
  for (int i = 0; i < 4; i++) {
    int mbase = tm + wr * 64 + i * 16 + hi * 4;
#pragma unroll
    for (int j = 0; j < 4; j++) {
      int col = tn + wc * 64 + j * 16 + lo;
      float bv = bias[col];
#pragma unroll
      for (int r = 0; r < 4; r++)
        out[(size_t)(mbase + r) * DIMX + col] = acc[i][j][r] + bv;
    }
  }
}

extern "C" void kernel_launch(void* const* d_in, const int* in_sizes, int n_in,
                              void* d_out, int out_size, void* d_ws, size_t ws_size,
                              hipStream_t stream) {
  const float* x     = (const float*)d_in[0];
  const float* w_qkv = (const float*)d_in[1];
  const float* w_out = (const float*)d_in[2];
  const float* b_out = (const float*)d_in[3];

  char* ws = (char*)d_ws;
  u16* xb    = (u16*)(ws);                         // 8 MB
  u16* wqkvb = (u16*)(ws + (size_t)8  * (1<<20));  // 6 MB
  u16* woutb = (u16*)(ws + (size_t)14 * (1<<20));  // 2 MB
  u16* Qd    = (u16*)(ws + (size_t)16 * (1<<20));  // 8 MB
  u16* Kdd   = (u16*)(ws + (size_t)24 * (1<<20));  // 8 MB
  u16* Vtd   = (u16*)(ws + (size_t)32 * (1<<20));  // 8 MB
  u16* Od    = (u16*)(ws + (size_t)40 * (1<<20));  // 8 MB

  cvt_kernel<<<(MTOT * DIMX / 4 + 255) / 256, 256, 0, stream>>>(x, xb, MTOT * DIMX / 4);
  cvt_kernel<<<(EQKV * DIMX / 4 + 255) / 256, 256, 0, stream>>>(w_qkv, wqkvb, EQKV * DIMX / 4);
  cvt_kernel<<<(DIMX * INNER / 4 + 255) / 256, 256, 0, stream>>>(w_out, woutb, DIMX * INNER / 4);

  gemm_qkv<<<dim3(EQKV / BN, MTOT / BM), 256, 0, stream>>>(xb, wqkvb, Qd, Kdd, Vtd);
  attn_kernel<<<dim3(SEQ / 128, BATCH * NHEAD), 256, 0, stream>>>(Qd, Kdd, Vtd, Od);
  gemm_out<<<dim3(DIMX / BN, MTOT / BM), 256, 0, stream>>>(Od, woutb, b_out, (float*)d_out);
}

// Round 6
// 133.151 us; speedup vs baseline: 1.8566x; 1.1665x over previous
//
#include <hip/hip_runtime.h>
#include <hip/hip_bf16.h>
#include <stdint.h>

typedef unsigned short u16;
typedef short bf16x8 __attribute__((ext_vector_type(8)));
typedef float f32x4 __attribute__((ext_vector_type(4)));
typedef float f32x16 __attribute__((ext_vector_type(16)));
typedef u16 u16x4 __attribute__((ext_vector_type(4)));
typedef unsigned int uint2v __attribute__((ext_vector_type(2)));

#define DIMX  1024
#define NHEAD 16
#define DH    64
#define INNER 1024
#define BATCH 2
#define SEQ   2048
#define MTOT  (BATCH*SEQ)   /* 4096 */
#define EQKV  (3*INNER)     /* 3072 */

__device__ __forceinline__ u16 f2bf(float f) {
  unsigned int x = __float_as_uint(f);
  unsigned int r = (x + 0x7FFFu + ((x >> 16) & 1u)) >> 16;
  return (u16)r;
}

__device__ __forceinline__ unsigned int cvtpk(float lo, float hi) {
  unsigned int r;
  asm("v_cvt_pk_bf16_f32 %0, %1, %2" : "=v"(r) : "v"(lo), "v"(hi));
  return r;
}

__device__ __forceinline__ void plswap_u(unsigned int& x, unsigned int& y) {
  auto r = __builtin_amdgcn_permlane32_swap(x, y, false, false);
  x = r[0]; y = r[1];
}
__device__ __forceinline__ void plswap_f2(float v, float& a, float& b) {
  unsigned int x = __float_as_uint(v), y = __float_as_uint(v);
  auto r = __builtin_amdgcn_permlane32_swap(x, y, false, false);
  a = __uint_as_float(r[0]); b = __uint_as_float(r[1]);
}

__device__ __forceinline__ void async16(void* lds, const void* g) {
  __builtin_amdgcn_global_load_lds(
      (const __attribute__((address_space(1))) unsigned int*)g,
      (__attribute__((address_space(3))) unsigned int*)lds,
      16, 0, 0);
}

// staging swizzle: 4 16B-units per 32-col row, unit ^= S(r), S(r)=(r^(r>>2))&3 -> ~2-way banks
__device__ __forceinline__ int swz4(int r) { return (r ^ (r >> 2)) & 3; }

// ---------------- fp32 -> bf16 convert ----------------
__global__ void cvt_kernel(const float* __restrict__ in, u16* __restrict__ out, int n4) {
  int i = blockIdx.x * blockDim.x + threadIdx.x;
  if (i < n4) {
    float4 v = ((const float4*)in)[i];
    u16x4 o;
    o[0] = f2bf(v.x); o[1] = f2bf(v.y); o[2] = f2bf(v.z); o[3] = f2bf(v.w);
    ((u16x4*)out)[i] = o;
  }
}

// ---------------- QKV projection GEMM (BK=32 dbuf prefetch) ----------------
// C[m][e] = sum_k X[m][k] W[e][k]; scatter to Q(scaled by dh^-.5*log2e), K, Vt(transposed).
// LDS: sA/sB [2][128*32] (32 KB total); V-epilogue reuses all 32 KB as a 128x128 bounce tile.
__global__ __launch_bounds__(256) void gemm_qkv(const u16* __restrict__ X, const u16* __restrict__ W,
                                                u16* __restrict__ Qo, u16* __restrict__ Ko,
                                                u16* __restrict__ Vt) {
  __shared__ short sAll[16384];
  short* sA = sAll;          // [2][128*32]
  short* sB = sAll + 8192;   // [2][128*32]
  const int tid = threadIdx.x;
  const int wv = tid >> 6, l = tid & 63;
  const int lo = l & 15, hi = l >> 4;
  const int wr = wv >> 1, wc = wv & 1;

  // XCD chunking (768 = 8*96, bijective), column-major: each XCD owns 3 B-panels (L2-resident)
  int lin = blockIdx.x;
  int wgid = (lin & 7) * 96 + (lin >> 3);
  const int bx = wgid / 32;          // N-tile 0..23
  const int by = wgid % 32;          // M-tile 0..31
  const int tn = bx * 128, tm = by * 128;

  f32x4 acc[4][4];
#pragma unroll
  for (int i = 0; i < 4; i++)
#pragma unroll
    for (int j = 0; j < 4; j++) acc[i][j] = (f32x4){0.f, 0.f, 0.f, 0.f};

  auto stage = [&](int buf, int kt) {
    int k0 = kt * 32;
    int off = buf * 4096;
#pragma unroll
    for (int c = 0; c < 2; c++) {
      int R0 = wv * 32 + c * 16;
      int r = R0 + (l >> 2);
      int sc = ((l & 3) ^ swz4(r)) * 8;
      async16(&sA[off + R0 * 32], &X[(size_t)(tm + r) * DIMX + k0 + sc]);
      async16(&sB[off + R0 * 32], &W[(size_t)(tn + r) * DIMX + k0 + sc]);
    }
  };

  stage(0, 0);
  __syncthreads();

  for (int kt = 0; kt < DIMX / 32; kt++) {
    const int buf = kt & 1;
    if (kt + 1 < DIMX / 32) stage(buf ^ 1, kt + 1);
    bf16x8 af[4], bf[4];
#pragma unroll
    for (int i = 0; i < 4; i++) {
      int r = wr * 64 + i * 16 + lo;
      af[i] = *(const bf16x8*)&sA[buf * 4096 + r * 32 + ((hi ^ swz4(r)) * 8)];
    }
#pragma unroll
    for (int j = 0; j < 4; j++) {
      int r = wc * 64 + j * 16 + lo;
      bf[j] = *(const bf16x8*)&sB[buf * 4096 + r * 32 + ((hi ^ swz4(r)) * 8)];
    }
#pragma unroll
    for (int i = 0; i < 4; i++)
#pragma unroll
      for (int j = 0; j < 4; j++)
        acc[i][j] = __builtin_amdgcn_mfma_f32_16x16x32_bf16(af[i], bf[j], acc[i][j], 0, 0, 0);
    __syncthreads();   // drains prefetch (overlapped with compute) + buffer handoff
  }

  const int cls = tn >> 10;          // 0=Q, 1=K, 2=V (BN=128 divides the 1024 boundaries)
  const float scale = 0.125f * 1.44269504088896f;  // dh^-0.5 * log2(e)

  if (cls < 2) {
    // direct scatter for Q/K
#pragma unroll
    for (int i = 0; i < 4; i++) {
      int mbase = tm + wr * 64 + i * 16 + hi * 4;
#pragma unroll
      for (int j = 0; j < 4; j++) {
        int e = tn + wc * 64 + j * 16 + lo;
        int e2 = e & 1023, h = e2 >> 6, d = e2 & 63;
#pragma unroll
        for (int r = 0; r < 4; r++) {
          int mm = mbase + r;
          int b = mm >> 11, n = mm & 2047;
          float v = acc[i][j][r];
          if (cls == 0)
            Qo[(((size_t)(b * NHEAD + h)) * SEQ + n) * DH + d] = f2bf(v * scale);
          else
            Ko[(((size_t)(b * NHEAD + h)) * SEQ + n) * DH + d] = f2bf(v);
        }
      }
    }
  } else {
    // V: bounce through LDS for coalesced transposed writes
    // sT[e][n] 128x128 bf16, unit(n>>3) ^= (e&15)
#pragma unroll
    for (int i = 0; i < 4; i++) {
#pragma unroll
      for (int j = 0; j < 4; j++) {
        int e = wc * 64 + j * 16 + lo;
#pragma unroll
        for (int r = 0; r < 4; r++) {
          int n = wr * 64 + i * 16 + hi * 4 + r;
          sAll[e * 128 + (((n >> 3) ^ (e & 15)) * 8) + (n & 7)] = (short)f2bf(acc[i][j][r]);
        }
      }
    }
    __syncthreads();
    int er = tid >> 1, half = tid & 1;
    int e2 = tn + er - 2048;
    int h = e2 >> 6, d = e2 & 63;
    int b = tm >> 11, nb = tm & 2047;
    u16* dst = &Vt[(((size_t)(b * NHEAD + h)) * DH + d) * SEQ + nb + half * 64];
#pragma unroll
    for (int k = 0; k < 8; k++) {
      int phys = (half * 8 + k) ^ (er & 15);
      bf16x8 v = *(const bf16x8*)&sAll[er * 128 + phys * 8];
      *(bf16x8*)&dst[k * 8] = v;
    }
  }
}

// ---------------- flash attention (unchanged from round 5) ----------------
__global__ __launch_bounds__(256) void attn_kernel(const u16* __restrict__ Q, const u16* __restrict__ Kd,
                                                   const u16* __restrict__ Vt, u16* __restrict__ O) {
  __shared__ short sK[2][64 * 64];
  __shared__ short sV[2][64 * 64];
  const int tid = threadIdx.x, wv = tid >> 6, l = tid & 63;
  const int l31 = l & 31, hi5 = l >> 5, l7 = l & 7;

  int lin = blockIdx.y * gridDim.x + blockIdx.x;
  int wgid = (lin & 7) * 64 + (lin >> 3);
  int bx = wgid & 15;
  int bh = wgid >> 4;

  const int qw = bx * 128 + wv * 32;
  const u16* Qb = Q + (size_t)bh * SEQ * DH;
  const u16* Kb = Kd + (size_t)bh * SEQ * DH;
  const u16* Vb = Vt + (size_t)bh * DH * SEQ;

  bf16x8 qf[4];
#pragma unroll
  for (int kd = 0; kd < 4; kd++)
    qf[kd] = *(const bf16x8*)&Qb[(size_t)(qw + l31) * DH + kd * 16 + hi5 * 8];

  f32x16 o0, o1;
#pragma unroll
  for (int r = 0; r < 16; r++) { o0[r] = 0.f; o1[r] = 0.f; }
  float mrun = -1e30f, lsum = 0.f;
  const float THR = 11.0f;

  auto stage = [&](int buf, int t) {
    int kv0 = t * 64;
#pragma unroll
    for (int c = 0; c < 2; c++) {
      int rbase = wv * 16 + c * 8;
      int gr = rbase + (l >> 3);
      int sc = ((l & 7) ^ (l >> 3)) * 8;
      async16(&sK[buf][rbase * 64], &Kb[(size_t)(kv0 + gr) * DH + sc]);
      async16(&sV[buf][rbase * 64], &Vb[(size_t)gr * SEQ + kv0 + sc]);
    }
  };

  stage(0, 0);
  __syncthreads();

  for (int t = 0; t < SEQ / 64; t++) {
    const int cur = t & 1;
    if (t + 1 < SEQ / 64) stage(cur ^ 1, t + 1);

    f32x16 s0, s1;
#pragma unroll
    for (int r = 0; r < 16; r++) { s0[r] = 0.f; s1[r] = 0.f; }
#pragma unroll
    for (int kd = 0; kd < 4; kd++) {
      int c16 = ((kd * 2 + hi5) ^ l7) * 8;
      bf16x8 k0 = *(const bf16x8*)&sK[cur][l31 * 64 + c16];
      bf16x8 k1 = *(const bf16x8*)&sK[cur][(32 + l31) * 64 + c16];
      s0 = __builtin_amdgcn_mfma_f32_32x32x16_bf16(k0, qf[kd], s0, 0, 0, 0);
      s1 = __builtin_amdgcn_mfma_f32_32x32x16_bf16(k1, qf[kd], s1, 0, 0, 0);
    }

    float tr[16];
#pragma unroll
    for (int r = 0; r < 16; r++) tr[r] = fmaxf(s0[r], s1[r]);
#pragma unroll
    for (int st = 8; st > 0; st >>= 1)
#pragma unroll
      for (int r = 0; r < st; r++) tr[r] = fmaxf(tr[r], tr[r + st]);
    float mxa, mxb;
    plswap_f2(tr[0], mxa, mxb);
    float mx = fmaxf(mxa, mxb);

    if (!__all(mx <= mrun + THR)) {
      float mnew = fmaxf(mrun, mx);
      float alpha = __builtin_amdgcn_exp2f(mrun - mnew);
      mrun = mnew;
      lsum *= alpha;
      o0 *= alpha;
      o1 *= alpha;
    }

    float sm[16];
#pragma unroll
    for (int r = 0; r < 16; r++) {
      s0[r] = __builtin_amdgcn_exp2f(s0[r] - mrun);
      s1[r] = __builtin_amdgcn_exp2f(s1[r] - mrun);
      sm[r] = s0[r] + s1[r];
    }
#pragma unroll
    for (int st = 8; st > 0; st >>= 1)
#pragma unroll
      for (int r = 0; r < st; r++) sm[r] += sm[r + st];
    lsum += sm[0];

    bf16x8 pa[4];
#pragma unroll
    for (int ks = 0; ks < 4; ks++) {
      const int sft = (ks & 1) * 8;
      float e0 = (ks < 2) ? s0[sft + 0] : s1[sft + 0];
      float e1 = (ks < 2) ? s0[sft + 1] : s1[sft + 1];
      float e2 = (ks < 2) ? s0[sft + 2] : s1[sft + 2];
      float e3 = (ks < 2) ? s0[sft + 3] : s1[sft + 3];
      float e4 = (ks < 2) ? s0[sft + 4] : s1[sft + 4];
      float e5 = (ks < 2) ? s0[sft + 5] : s1[sft + 5];
      float e6 = (ks < 2) ? s0[sft + 6] : s1[sft + 6];
      float e7 = (ks < 2) ? s0[sft + 7] : s1[sft + 7];
      unsigned int w0 = cvtpk(e0, e1);
      unsigned int w1 = cvtpk(e2, e3);
      unsigned int w2 = cvtpk(e4, e5);
      unsigned int w3 = cvtpk(e6, e7);
      plswap_u(w0, w2);
      plswap_u(w1, w3);
      union { unsigned int w[4]; bf16x8 v; } u;
      u.w[0] = w0; u.w[1] = w1; u.w[2] = w2; u.w[3] = w3;
      pa[ks] = u.v;
    }

#pragma unroll
    for (int ks = 0; ks < 4; ks++) {
      int c16 = ((ks * 2 + hi5) ^ l7) * 8;
      bf16x8 v0 = *(const bf16x8*)&sV[cur][l31 * 64 + c16];
      bf16x8 v1 = *(const bf16x8*)&sV[cur][(32 + l31) * 64 + c16];
      o0 = __builtin_amdgcn_mfma_f32_32x32x16_bf16(v0, pa[ks], o0, 0, 0, 0);
      o1 = __builtin_amdgcn_mfma_f32_32x32x16_bf16(v1, pa[ks], o1, 0, 0, 0);
    }
    __syncthreads();
  }

  float la, lb;
  plswap_f2(lsum, la, lb);
  float inv = 1.0f / (la + lb);

  int b = bh >> 4, h = bh & 15;
  int q = qw + l31;
  size_t orow = ((size_t)(b * SEQ + q)) * INNER + h * 64;
#pragma unroll
  for (int half = 0; half < 2; half++) {
    const f32x16& oo = half ? o1 : o0;
#pragma unroll
    for (int g = 0; g < 4; g++) {
      uint2v pk2;
      pk2[0] = cvtpk(oo[g * 4 + 0] * inv, oo[g * 4 + 1] * inv);
      pk2[1] = cvtpk(oo[g * 4 + 2] * inv, oo[g * 4 + 3] * inv);
      int dv = half * 32 + g * 8 + 4 * hi5;
      *(uint2v*)&O[orow + dv] = pk2;
    }
  }
}

// ---------------- output projection GEMM (BK=32 dbuf prefetch) ----------------
__global__ __launch_bounds__(256) void gemm_out(const u16* __restrict__ A, const u16* __restrict__ W,
                                                const float* __restrict__ bias, float* __restrict__ out) {
  __shared__ short sAll[16384];
  short* sA = sAll;
  short* sB = sAll + 8192;
  const int tid = threadIdx.x;
  const int wv = tid >> 6, l = tid & 63;
  const int lo = l & 15, hi = l >> 4;
  const int wr = wv >> 1, wc = wv & 1;

  // XCD chunking (256 = 8*32): each XCD owns one N-column of tiles
  int lin = blockIdx.x;
  int wgid = (lin & 7) * 32 + (lin >> 3);
  const int bx = wgid / 32;          // 0..7
  const int by = wgid % 32;          // 0..31
  const int tn = bx * 128, tm = by * 128;

  f32x4 acc[4][4];
#pragma unroll
  for (int i = 0; i < 4; i++)
#pragma unroll
    for (int j = 0; j < 4; j++) acc[i][j] = (f32x4){0.f, 0.f, 0.f, 0.f};

  auto stage = [&](int buf, int kt) {
    int k0 = kt * 32;
    int off = buf * 4096;
#pragma unroll
    for (int c = 0; c < 2; c++) {
      int R0 = wv * 32 + c * 16;
      int r = R0 + (l >> 2);
      int sc = ((l & 3) ^ swz4(r)) * 8;
      async16(&sA[off + R0 * 32], &A[(size_t)(tm + r) * INNER + k0 + sc]);
      async16(&sB[off + R0 * 32], &W[(size_t)(tn + r) * INNER + k0 + sc]);
    }
  };

  stage(0, 0);
  __syncthreads();

  for (int kt = 0; kt < INNER / 32; kt++) {
    const int buf = kt & 1;
    if (kt + 1 < INNER / 32) stage(buf ^ 1, kt + 1);
    bf16x8 af[4], bf[4];
#pragma unroll
    for (int i = 0; i < 4; i++) {
      int r = wr * 64 + i * 16 + lo;
      af[i] = *(const bf16x8*)&sA[buf * 4096 + r * 32 + ((hi ^ swz4(r)) * 8)];
    }
#pragma unroll
    for (int j = 0; j < 4; j++) {
      int r = wc * 64 + j * 16 + lo;
      bf[j] = *(const bf16x8*)&sB[buf * 4096 + r * 32 + ((hi ^ swz4(r)) * 8)];
    }
#pragma unroll
    for (int i = 0; i < 4; i++)
#pragma unroll
      for (int j = 0; j < 4; j++)
        acc[i][j] = __builtin_amdgcn_mfma_f32_16x16x32_bf16(af[i], bf[j], acc[i][j], 0, 0, 0);
    __syncthreads();
  }

#pragma unroll
  for (int i = 0; i < 4; i++) {
    int mbase = tm + wr * 64 + i * 16 + hi * 4;
#pragma unroll
    for (int j = 0; j < 4; j++) {
      int col = tn + wc * 64 + j * 16 + lo;
      float bv = bias[col];
#pragma unroll
      for (int r = 0; r < 4; r++)
        out[(size_t)(mbase + r) * DIMX + col] = acc[i][j][r] + bv;
    }
  }
}

extern "C" void kernel_launch(void* const* d_in, const int* in_sizes, int n_in,
                              void* d_out, int out_size, void* d_ws, size_t ws_size,
                              hipStream_t stream) {
  const float* x     = (const float*)d_in[0];
  const float* w_qkv = (const float*)d_in[1];
  const float* w_out = (const float*)d_in[2];
  const float* b_out = (const float*)d_in[3];

  char* ws = (char*)d_ws;
  u16* xb    = (u16*)(ws);                         // 8 MB
  u16* wqkvb = (u16*)(ws + (size_t)8  * (1<<20));  // 6 MB
  u16* woutb = (u16*)(ws + (size_t)14 * (1<<20));  // 2 MB
  u16* Qd    = (u16*)(ws + (size_t)16 * (1<<20));  // 8 MB
  u16* Kdd   = (u16*)(ws + (size_t)24 * (1<<20));  // 8 MB
  u16* Vtd   = (u16*)(ws + (size_t)32 * (1<<20));  // 8 MB
  u16* Od    = (u16*)(ws + (size_t)40 * (1<<20));  // 8 MB

  cvt_kernel<<<(MTOT * DIMX / 4 + 255) / 256, 256, 0, stream>>>(x, xb, MTOT * DIMX / 4);
  cvt_kernel<<<(EQKV * DIMX / 4 + 255) / 256, 256, 0, stream>>>(w_qkv, wqkvb, EQKV * DIMX / 4);
  cvt_kernel<<<(DIMX * INNER / 4 + 255) / 256, 256, 0, stream>>>(w_out, woutb, DIMX * INNER / 4);

  gemm_qkv<<<768, 256, 0, stream>>>(xb, wqkvb, Qd, Kdd, Vtd);
  attn_kernel<<<dim3(SEQ / 128, BATCH * NHEAD), 256, 0, stream>>>(Qd, Kdd, Vtd, Od);
  gemm_out<<<256, 256, 0, stream>>>(Od, woutb, b_out, (float*)d_out);
}